// Round 2
// baseline (225.794 us; speedup 1.0000x reference)
//
#include <hip/hip_runtime.h>
#include <hip/hip_bf16.h>
#include <stdint.h>

using bf16x8 = __attribute__((ext_vector_type(8))) short;
using f32x4  = __attribute__((ext_vector_type(4))) float;

#define N_NODES  50000
#define K1       768
#define D1       512
#define NPAIR    16384
#define NOUT     97
#define NOUT_PAD 112
#define MTILES   391          // ceil(50000/128)
#define NTILES   4
#define NWG      (MTILES * NTILES)   // 1564
#define WGPX     196                 // ceil(1564/8)

__device__ __forceinline__ uint16_t f2bf(float f) {
    uint32_t u = __builtin_bit_cast(uint32_t, f);
    return (uint16_t)((u + 0x7fffu + ((u >> 16) & 1u)) >> 16);  // RNE
}

// packed RNE f32->bf16 pair (no builtin on gfx950 -> inline asm, T12 recipe)
__device__ __forceinline__ uint32_t cvt_pk_bf16(float lo, float hi) {
    uint32_t r;
    asm("v_cvt_pk_bf16_f32 %0, %1, %2" : "=v"(r) : "v"(lo), "v"(hi));
    return r;
}

// ---- convert: W1[768][512] -> W1t bf16 [512][768]; Wp[1024][97] -> Wpt bf16 [112][1024] (zero-pad) ----
__global__ void k_convert(const float* __restrict__ W1, const float* __restrict__ Wp,
                          uint16_t* __restrict__ W1t, uint16_t* __restrict__ Wpt) {
    int idx = blockIdx.x * 256 + threadIdx.x;
    const int n1 = D1 * K1;
    if (idx < n1) {
        int c = idx / K1, k = idx - c * K1;
        W1t[idx] = f2bf(W1[k * D1 + c]);
    } else {
        int j = idx - n1;
        if (j < NOUT_PAD * 1024) {
            int c = j >> 10, k = j & 1023;
            Wpt[j] = (c < NOUT) ? f2bf(Wp[k * NOUT + c]) : (uint16_t)0;
        }
    }
}

// ---- GEMM1: H[50000][512] = relu(A[50000][768] @ W1 + b1) ----
// 128x128 tile, BK=64, 4 waves 2x2, fused fp32->bf16 via v_cvt_pk, XOR-swizzled LDS,
// XCD-grouped block mapping so the 4 n-blocks of one m-tile share an L2.
__global__ __launch_bounds__(256) void k_gemm1(const float* __restrict__ A,
        const uint16_t* __restrict__ W1t, const float* __restrict__ bias1,
        uint16_t* __restrict__ H) {
    __shared__ uint16_t lds_a[128 * 64];
    __shared__ uint16_t lds_b[128 * 64];

    // block swizzle: xcd = bid&7 gets contiguous tile chunk; n fastest within chunk
    const int bid = blockIdx.x;
    const int tt = (bid & 7) * WGPX + (bid >> 3);
    if (tt >= NWG) return;
    const int m0 = (tt >> 2) * 128, n0 = (tt & 3) * 128;

    const int t = threadIdx.x;
    const int lane = t & 63, wave = t >> 6;
    const int wm = wave >> 1, wn = wave & 1;
    const int cl = lane & 15, kh = lane >> 4;

    f32x4 acc[4][4];
    const f32x4 z = {0.f, 0.f, 0.f, 0.f};
    #pragma unroll
    for (int m = 0; m < 4; ++m)
        #pragma unroll
        for (int n = 0; n < 4; ++n) acc[m][n] = z;

    // staging: thread t covers row r = t>>1, k-half h = t&1 (32 elems = 4 chunks of 8)
    const int r = t >> 1, h = t & 1;
    int row_g = m0 + r; if (row_g >= N_NODES) row_g = N_NODES - 1;
    const float*    asrc = A   + (size_t)row_g   * K1 + h * 32;
    const uint16_t* bsrc = W1t + (size_t)(n0 + r) * K1 + h * 32;
    uint16_t* adst = &lds_a[r * 64];
    uint16_t* bdst = &lds_b[r * 64];
    const int r7 = r & 7;

    // frag read offsets (element units); chunk_phys = chunk_log ^ (row&7), row&7 == cl&7
    const int c7 = cl & 7;
    const int ca0 = ((kh) ^ c7) * 8, ca1 = ((kh + 4) ^ c7) * 8;
    int arow[4], brow[4];
    #pragma unroll
    for (int m = 0; m < 4; ++m) arow[m] = (wm * 64 + m * 16 + cl) * 64;
    #pragma unroll
    for (int n = 0; n < 4; ++n) brow[n] = (wn * 64 + n * 16 + cl) * 64;

    float4 fa[8];
    uint4  fb[4];
    {   // prefetch kt=0
        const float4* ap = (const float4*)asrc;
        #pragma unroll
        for (int i = 0; i < 8; ++i) fa[i] = ap[i];
        const uint4* bp = (const uint4*)bsrc;
        #pragma unroll
        for (int j = 0; j < 4; ++j) fb[j] = bp[j];
    }

    for (int kt = 0; kt < K1 / 64; ++kt) {
        // cvt current A regs to packed bf16
        uint32_t pk[16];
        #pragma unroll
        for (int i = 0; i < 8; ++i) {
            pk[2 * i]     = cvt_pk_bf16(fa[i].x, fa[i].y);
            pk[2 * i + 1] = cvt_pk_bf16(fa[i].z, fa[i].w);
        }
        __syncthreads();   // previous tile's reads done
        #pragma unroll
        for (int j = 0; j < 4; ++j) {
            const int cp = ((h * 4 + j) ^ r7) * 8;   // swizzled chunk
            *(uint4*)(adst + cp) = *(uint4*)&pk[4 * j];
            *(uint4*)(bdst + cp) = fb[j];
        }
        __syncthreads();   // tile staged

        // prefetch next tile's globals; HBM latency hides under the MFMA cluster
        if (kt + 1 < K1 / 64) {
            const float4* ap = (const float4*)(asrc + (kt + 1) * 64);
            #pragma unroll
            for (int i = 0; i < 8; ++i) fa[i] = ap[i];
            const uint4* bp = (const uint4*)(bsrc + (kt + 1) * 64);
            #pragma unroll
            for (int j = 0; j < 4; ++j) fb[j] = bp[j];
        }

        #pragma unroll
        for (int half = 0; half < 2; ++half) {
            const int co = half ? ca1 : ca0;
            bf16x8 af[4], bfr[4];
            #pragma unroll
            for (int m = 0; m < 4; ++m) af[m] = *(const bf16x8*)&lds_a[arow[m] + co];
            #pragma unroll
            for (int n = 0; n < 4; ++n) bfr[n] = *(const bf16x8*)&lds_b[brow[n] + co];
            #pragma unroll
            for (int m = 0; m < 4; ++m)
                #pragma unroll
                for (int n = 0; n < 4; ++n)
                    acc[m][n] = __builtin_amdgcn_mfma_f32_16x16x32_bf16(af[m], bfr[n], acc[m][n], 0, 0, 0);
        }
    }

    // epilogue: +bias, relu, bf16 store.  C layout: col = lane&15, row = (lane>>4)*4 + reg
    float bv[4]; int bcol[4];
    #pragma unroll
    for (int n = 0; n < 4; ++n) { bcol[n] = n0 + wn * 64 + n * 16 + cl; bv[n] = bias1[bcol[n]]; }
    #pragma unroll
    for (int m = 0; m < 4; ++m) {
        int rbase = m0 + wm * 64 + m * 16 + kh * 4;
        #pragma unroll
        for (int rr = 0; rr < 4; ++rr) {
            int row = rbase + rr;
            if (row < N_NODES) {
                #pragma unroll
                for (int n = 0; n < 4; ++n) {
                    float v = acc[m][n][rr] + bv[n];
                    H[(size_t)row * D1 + bcol[n]] = f2bf(fmaxf(v, 0.f));
                }
            }
        }
    }
}

// ---- GEMM2: out[16384][97] = concat(H[head], H[tail]) @ Wp + bp ----
__global__ __launch_bounds__(256) void k_gemm2(const uint16_t* __restrict__ H,
        const uint16_t* __restrict__ Wpt, const float* __restrict__ bp,
        const int* __restrict__ head, const int* __restrict__ tail,
        float* __restrict__ out) {
    __shared__ uint16_t lds_w[NOUT_PAD][40];
    const int t = threadIdx.x;
    const int lane = t & 63, wave = t >> 6;
    const int cl = lane & 15, kh = lane >> 4;
    const int rowbase = blockIdx.x * 64 + wave * 16;
    const int i_l = rowbase + cl;
    const int nodeH = head[i_l], nodeT = tail[i_l];
    const uint16_t* hH = H + (size_t)nodeH * D1 + kh * 8;
    const uint16_t* hT = H + (size_t)nodeT * D1 + kh * 8;

    f32x4 acc[7];
    const f32x4 z = {0.f, 0.f, 0.f, 0.f};
    #pragma unroll
    for (int n = 0; n < 7; ++n) acc[n] = z;

    const int wrow = t >> 1, whalf = t & 1;
    const uint16_t* wsrc = Wpt + (size_t)wrow * 1024 + whalf * 16;
    uint16_t* wdst = &lds_w[wrow][whalf * 16];

    for (int kb = 0; kb < 32; ++kb) {
        uint4 w0 = {0,0,0,0}, w1 = {0,0,0,0};
        if (t < 224) {
            const uint4* wp4 = (const uint4*)(wsrc + kb * 32);
            w0 = wp4[0]; w1 = wp4[1];
        }
        bf16x8 af = (kb < 16) ? *(const bf16x8*)(hH + kb * 32)
                              : *(const bf16x8*)(hT + (kb - 16) * 32);
        __syncthreads();
        if (t < 224) { ((uint4*)wdst)[0] = w0; ((uint4*)wdst)[1] = w1; }
        __syncthreads();
        #pragma unroll
        for (int n = 0; n < 7; ++n) {
            bf16x8 bfr = *(const bf16x8*)&lds_w[n * 16 + cl][kh * 8];
            acc[n] = __builtin_amdgcn_mfma_f32_16x16x32_bf16(af, bfr, acc[n], 0, 0, 0);
        }
    }
    #pragma unroll
    for (int n = 0; n < 7; ++n) {
        int col = n * 16 + cl;
        if (col < NOUT) {
            float bb = bp[col];
            #pragma unroll
            for (int rr = 0; rr < 4; ++rr) {
                int i = rowbase + kh * 4 + rr;
                out[(size_t)i * NOUT + col] = acc[n][rr] + bb;
            }
        }
    }
}

extern "C" void kernel_launch(void* const* d_in, const int* in_sizes, int n_in,
                              void* d_out, int out_size, void* d_ws, size_t ws_size,
                              hipStream_t stream) {
    const float* node_features = (const float*)d_in[0];
    // d_in[1] = edge_features (unused: message passing is an exact identity)
    const float* W1   = (const float*)d_in[2];
    const float* b1   = (const float*)d_in[3];
    const float* Wp   = (const float*)d_in[4];
    const float* bp   = (const float*)d_in[5];
    // d_in[6] = src (unused), d_in[7] = dst (unused)
    const int* head   = (const int*)d_in[8];
    const int* tail   = (const int*)d_in[9];
    float* out = (float*)d_out;

    char* ws = (char*)d_ws;
    uint16_t* H   = (uint16_t*)ws;
    uint16_t* W1t = (uint16_t*)(ws + (size_t)N_NODES * D1 * 2);
    uint16_t* Wpt = (uint16_t*)(ws + (size_t)N_NODES * D1 * 2 + (size_t)D1 * K1 * 2);

    const int convN = D1 * K1 + NOUT_PAD * 1024;
    k_convert<<<(convN + 255) / 256, 256, 0, stream>>>(W1, Wp, W1t, Wpt);

    k_gemm1<<<WGPX * 8, 256, 0, stream>>>(node_features, W1t, b1, H);

    k_gemm2<<<NPAIR / 64, 256, 0, stream>>>(H, Wpt, bp, head, tail, out);
}